// Round 4
// baseline (527.159 us; speedup 1.0000x reference)
//
#include <hip/hip_runtime.h>
#include <math.h>

#define B_ 64
#define N_ 2048
#define O_ 32
#define I_ 16
#define D_ 32
#define OD_ 1024
#define BLK 1024   // 16 waves = 2 b-groups x 8 col-groups

typedef __attribute__((ext_vector_type(8))) short bf16x8;
typedef __attribute__((ext_vector_type(4))) float f32x4;

union FragU { unsigned u[4]; uint4 v; bf16x8 f; };

__device__ __forceinline__ void dk_split(float f, unsigned &h, unsigned &l) {
  unsigned u = __float_as_uint(f);
  h = u & 0xffff0000u;
  float lo = f - __uint_as_float(h);
  l = __float_as_uint(lo) >> 16;
}

__device__ __forceinline__ void dk_split16(float f, unsigned short &h,
                                           unsigned short &l) {
  unsigned u = __float_as_uint(f);
  unsigned hu = u & 0xffff0000u;
  h = (unsigned short)(u >> 16);
  float lo = f - __uint_as_float(hu);
  l = (unsigned short)(__float_as_uint(lo) >> 16);
}

__device__ __forceinline__ unsigned pk(unsigned short e0, unsigned short e1) {
  return (unsigned)e0 | ((unsigned)e1 << 16);
}

// ---- merged prep: blocks [0,8192) pack W -> WP, [8192,8704) pack x -> XP ----
// WP u4 idx = (((n*32+o)*2 + dhalf)*4 + sel*2 + qp)*16 + c
// XP u4 idx = (((bg*2048+n)*2 + sel)*2 + qp)*16 + c ; b = bg*16 + c
__global__ __launch_bounds__(256) void prep_all(const float* __restrict__ W,
                                                const float* __restrict__ x,
                                                uint4* __restrict__ WP,
                                                uint4* __restrict__ XP) {
  if (blockIdx.x < 8192) {
    int t = blockIdx.x * 256 + threadIdx.x;  // 2,097,152 = n*o*d
    int d = t & 31, o = (t >> 5) & 31, n = t >> 10;
    const float* wp = W + ((size_t)(n * O_ + o) * I_) * D_ + d;
    unsigned short hh[I_], ll[I_];
#pragma unroll
    for (int i = 0; i < I_; ++i) dk_split16(wp[i * D_], hh[i], ll[i]);
    int c = d & 15, dhalf = d >> 4;
    size_t base = ((size_t)(n * O_ + o) * 2 + dhalf) * 4;
#pragma unroll
    for (int sel = 0; sel < 2; ++sel) {
      const unsigned short* e = sel ? ll : hh;
#pragma unroll
      for (int qp = 0; qp < 2; ++qp) {
        uint4 u;
        u.x = pk(e[qp * 8 + 0], e[qp * 8 + 1]);
        u.y = pk(e[qp * 8 + 2], e[qp * 8 + 3]);
        u.z = pk(e[qp * 8 + 4], e[qp * 8 + 5]);
        u.w = pk(e[qp * 8 + 6], e[qp * 8 + 7]);
        WP[(base + sel * 2 + qp) * 16 + c] = u;
      }
    }
  } else {
    int t = (blockIdx.x - 8192) * 256 + threadIdx.x;  // 131,072
    int c = t & 15, n = (t >> 4) & 2047, bg = t >> 15;
    const float* xp = x + ((size_t)(bg * 16 + c) * N_ + n) * I_;
    unsigned short hh[I_], ll[I_];
#pragma unroll
    for (int i = 0; i < I_; ++i) dk_split16(xp[i], hh[i], ll[i]);
    size_t base = ((size_t)bg * N_ + n) * 4;
#pragma unroll
    for (int sel = 0; sel < 2; ++sel) {
      const unsigned short* e = sel ? ll : hh;
#pragma unroll
      for (int qp = 0; qp < 2; ++qp) {
        uint4 u;
        u.x = pk(e[qp * 8 + 0], e[qp * 8 + 1]);
        u.y = pk(e[qp * 8 + 2], e[qp * 8 + 3]);
        u.z = pk(e[qp * 8 + 4], e[qp * 8 + 5]);
        u.w = pk(e[qp * 8 + 6], e[qp * 8 + 7]);
        XP[(base + sel * 2 + qp) * 16 + c] = u;
      }
    }
  }
}

// ---- fused routing pass: 16 waves = 2 bgl x 8 cg; wave pairs share WP ----
// Per n: u_hat tile = mfma(A_hi, B) + mfma(A_lo, B), B=[wh|wl].
template <int UNIFORM>
__global__ __launch_bounds__(BLK, 4) void mfma_pass2(
    const uint4* __restrict__ XP, const uint4* __restrict__ WP,
    const float* __restrict__ v, float* __restrict__ partial, int NC) {
  const int tid = threadIdx.x;
  const int lane = tid & 63;
  const int w = tid >> 6;       // 0..15
  const int bgl = w & 1;        // b-group within block
  const int cg = w >> 1;        // col-group 0..7
  const int q = lane >> 4;
  const int c = lane & 15;
  const int qp = q & 1;
  const int ch = blockIdx.x;
  const int bg = blockIdx.y * 2 + bgl;  // global b-group 0..3
  const int bq = (q >> 1) * 32 + qp * 16 + c;

  __shared__ float ls_logit[32 * O_];
  __shared__ float ls_c[32 * O_];

  f32x4 s_t[8];
#pragma unroll
  for (int ct = 0; ct < 8; ++ct) s_t[ct] = (f32x4){0.f, 0.f, 0.f, 0.f};

  const int n0 = ch * NC;
  for (int nl = 0; nl < NC; ++nl) {
    const int n = n0 + nl;

    const uint4* xb = XP + (((size_t)bg * N_ + n) * 4 + qp) * 16 + c;
    FragU ahi, alo;
    ahi.v = xb[0];
    alo.v = xb[32];

    const uint4* wb = WP + (size_t)n * 4096 + cg * 8 * 64 + bq;
    FragU bfr[8];
#pragma unroll
    for (int ct = 0; ct < 8; ++ct) bfr[ct].v = wb[ct * 64];

    f32x4 u_t[8];
#pragma unroll
    for (int ct = 0; ct < 8; ++ct) {
      if (UNIFORM) {
        s_t[ct] = __builtin_amdgcn_mfma_f32_16x16x32_bf16(ahi.f, bfr[ct].f, s_t[ct], 0, 0, 0);
        s_t[ct] = __builtin_amdgcn_mfma_f32_16x16x32_bf16(alo.f, bfr[ct].f, s_t[ct], 0, 0, 0);
      } else {
        f32x4 acc = (f32x4){0.f, 0.f, 0.f, 0.f};
        acc = __builtin_amdgcn_mfma_f32_16x16x32_bf16(ahi.f, bfr[ct].f, acc, 0, 0, 0);
        u_t[ct] = __builtin_amdgcn_mfma_f32_16x16x32_bf16(alo.f, bfr[ct].f, acc, 0, 0, 0);
      }
    }

    if (!UNIFORM) {
      // logits: logit[b,o] = sum_d u[b,o,d]*v[b,o,d]; C-layout row=q*4+r, col=c
#pragma unroll
      for (int ol = 0; ol < 4; ++ol) {
        float lg[4] = {0.f, 0.f, 0.f, 0.f};
#pragma unroll
        for (int hf = 0; hf < 2; ++hf) {
          int ct = ol * 2 + hf;
          int odc = cg * 128 + ct * 16 + c;
#pragma unroll
          for (int r = 0; r < 4; ++r)
            lg[r] = fmaf(u_t[ct][r], v[(size_t)(bg * 16 + q * 4 + r) * OD_ + odc], lg[r]);
        }
#pragma unroll
        for (int r = 0; r < 4; ++r) {
#pragma unroll
          for (int m = 1; m < 16; m <<= 1) lg[r] += __shfl_xor(lg[r], m);
        }
        if (c == 0) {
#pragma unroll
          for (int r = 0; r < 4; ++r)
            ls_logit[(bgl * 16 + q * 4 + r) * O_ + cg * 4 + ol] = lg[r];
        }
      }
      __syncthreads();
      // softmax over o: 1024 threads = 32 b x 32 o
      {
        int b_l = tid >> 5, o = tid & 31;
        float l = ls_logit[b_l * O_ + o];
        float mx = l;
#pragma unroll
        for (int m = 16; m >= 1; m >>= 1) mx = fmaxf(mx, __shfl_xor(mx, m));
        float e = __expf(l - mx);
        float sm = e;
#pragma unroll
        for (int m = 16; m >= 1; m >>= 1) sm += __shfl_xor(sm, m);
        ls_c[b_l * O_ + o] = e / sm;
      }
      __syncthreads();
      // s += c * u
#pragma unroll
      for (int ol = 0; ol < 4; ++ol) {
        int o = cg * 4 + ol;
        float cc[4];
#pragma unroll
        for (int r = 0; r < 4; ++r) cc[r] = ls_c[(bgl * 16 + q * 4 + r) * O_ + o];
#pragma unroll
        for (int hf = 0; hf < 2; ++hf) {
          int ct = ol * 2 + hf;
#pragma unroll
          for (int r = 0; r < 4; ++r)
            s_t[ct][r] = fmaf(cc[r], u_t[ct][r], s_t[ct][r]);
        }
      }
    }
  }

  const float scale = UNIFORM ? (1.f / 32.f) : 1.f;
#pragma unroll
  for (int ct = 0; ct < 8; ++ct) {
#pragma unroll
    for (int r = 0; r < 4; ++r) {
      partial[((size_t)ch * B_ + bg * 16 + q * 4 + r) * OD_ + cg * 128 + ct * 16 + c] =
          s_t[ct][r] * scale;
    }
  }
}

// ---- fallback (round-2 path, used only if ws too small for WP/XP) ----
template <int UNIFORM>
__global__ __launch_bounds__(512, 4) void mfma_pass_fb(
    const float* __restrict__ x, const float* __restrict__ W,
    const float* __restrict__ v, float* __restrict__ partial, int NC) {
  const int tid = threadIdx.x;
  const int lane = tid & 63;
  const int cg = tid >> 6;
  const int q = lane >> 4;
  const int c = lane & 15;
  const int ch = blockIdx.x;
  const int bg = blockIdx.y;

  __shared__ float ls_logit[16 * O_];
  __shared__ float ls_c[16 * O_];

  f32x4 s_t[8];
#pragma unroll
  for (int ct = 0; ct < 8; ++ct) s_t[ct] = (f32x4){0.f, 0.f, 0.f, 0.f};

  const int n0 = ch * NC;
  const int ih = (q & 1) * 8;
  const float* xrow = x + ((size_t)(bg * 16 + c) * N_) * I_ + ih;

  for (int nl = 0; nl < NC; ++nl) {
    const int n = n0 + nl;
    const float* xp = xrow + (size_t)n * I_;
    float4 xv0 = *(const float4*)xp;
    float4 xv1 = *(const float4*)(xp + 4);
    float xv[8] = {xv0.x, xv0.y, xv0.z, xv0.w, xv1.x, xv1.y, xv1.z, xv1.w};
    FragU a1;
#pragma unroll
    for (int p = 0; p < 4; ++p) {
      unsigned h0, l0, h1, l1;
      dk_split(xv[2 * p], h0, l0);
      dk_split(xv[2 * p + 1], h1, l1);
      a1.u[p] = (q < 2) ? ((h0 >> 16) | h1) : (l0 | (l1 << 16));
    }
    f32x4 u_t[8];
#pragma unroll
    for (int ct = 0; ct < 8; ++ct) {
      const int o = cg * 4 + (ct >> 1);
      const int d = (ct & 1) * 16 + c;
      const float* wp = W + (((size_t)n * O_ + o) * I_ + ih) * D_ + d;
      FragU b1, b2;
#pragma unroll
      for (int p = 0; p < 4; ++p) {
        unsigned h0, l0, h1, l1;
        dk_split(wp[(2 * p) * D_], h0, l0);
        dk_split(wp[(2 * p + 1) * D_], h1, l1);
        b1.u[p] = (h0 >> 16) | h1;
        b2.u[p] = l0 | (l1 << 16);
      }
      if (UNIFORM) {
        s_t[ct] = __builtin_amdgcn_mfma_f32_16x16x32_bf16(a1.f, b1.f, s_t[ct], 0, 0, 0);
        s_t[ct] = __builtin_amdgcn_mfma_f32_16x16x32_bf16(a1.f, b2.f, s_t[ct], 0, 0, 0);
      } else {
        f32x4 acc = (f32x4){0.f, 0.f, 0.f, 0.f};
        acc = __builtin_amdgcn_mfma_f32_16x16x32_bf16(a1.f, b1.f, acc, 0, 0, 0);
        u_t[ct] = __builtin_amdgcn_mfma_f32_16x16x32_bf16(a1.f, b2.f, acc, 0, 0, 0);
      }
    }
    if (!UNIFORM) {
#pragma unroll
      for (int ol = 0; ol < 4; ++ol) {
        float lg[4] = {0.f, 0.f, 0.f, 0.f};
#pragma unroll
        for (int hf = 0; hf < 2; ++hf) {
          int ct = ol * 2 + hf;
          int odc = cg * 128 + ct * 16 + c;
#pragma unroll
          for (int r = 0; r < 4; ++r)
            lg[r] = fmaf(u_t[ct][r], v[(size_t)(bg * 16 + q * 4 + r) * OD_ + odc], lg[r]);
        }
#pragma unroll
        for (int r = 0; r < 4; ++r) {
#pragma unroll
          for (int m = 1; m < 16; m <<= 1) lg[r] += __shfl_xor(lg[r], m);
        }
        if (c == 0) {
#pragma unroll
          for (int r = 0; r < 4; ++r)
            ls_logit[(q * 4 + r) * O_ + cg * 4 + ol] = lg[r];
        }
      }
      __syncthreads();
      {
        int b_l = tid >> 5, o = tid & 31;
        float l = ls_logit[b_l * O_ + o];
        float mx = l;
#pragma unroll
        for (int m = 16; m >= 1; m >>= 1) mx = fmaxf(mx, __shfl_xor(mx, m));
        float e = __expf(l - mx);
        float sm = e;
#pragma unroll
        for (int m = 16; m >= 1; m >>= 1) sm += __shfl_xor(sm, m);
        ls_c[b_l * O_ + o] = e / sm;
      }
      __syncthreads();
#pragma unroll
      for (int ol = 0; ol < 4; ++ol) {
        int o = cg * 4 + ol;
        float cc[4];
#pragma unroll
        for (int r = 0; r < 4; ++r) cc[r] = ls_c[(q * 4 + r) * O_ + o];
#pragma unroll
        for (int hf = 0; hf < 2; ++hf) {
          int ct = ol * 2 + hf;
#pragma unroll
          for (int r = 0; r < 4; ++r)
            s_t[ct][r] = fmaf(cc[r], u_t[ct][r], s_t[ct][r]);
        }
      }
    }
  }

  const float scale = UNIFORM ? (1.f / 32.f) : 1.f;
#pragma unroll
  for (int ct = 0; ct < 8; ++ct) {
#pragma unroll
    for (int r = 0; r < 4; ++r) {
      partial[((size_t)ch * B_ + bg * 16 + q * 4 + r) * OD_ + cg * 128 + ct * 16 + c] =
          s_t[ct][r] * scale;
    }
  }
}

// Sum partials over chunks, squash along d; out = (prev?:0) + squash(s)
__global__ __launch_bounds__(256) void reduce_squash(
    const float* __restrict__ part, int chunks,
    const float* __restrict__ prev, float* __restrict__ out) {
  int g = blockIdx.x * 256 + threadIdx.x;
  float s = 0.f;
  for (int ch = 0; ch < chunks; ++ch) s += part[(size_t)ch * 65536 + g];
  float sq = s * s;
#pragma unroll
  for (int m = 16; m >= 1; m >>= 1) sq += __shfl_xor(sq, m, 32);
  float scale = sq / ((1.f + sq) * (sqrtf(sq) + 1e-6f));
  float r = s * scale;
  if (prev) r += prev[g];
  out[g] = r;
}

extern "C" void kernel_launch(void* const* d_in, const int* in_sizes, int n_in,
                              void* d_out, int out_size, void* d_ws,
                              size_t ws_size, hipStream_t stream) {
  const float* x = (const float*)d_in[0];
  const float* W = (const float*)d_in[1];
  float* out = (float*)d_out;

  const size_t XP_FLOATS = 4ull * 2048 * 4 * 16 * 4;        // 2,097,152
  const size_t WP_FLOATS = 2048ull * 32 * 2 * 4 * 16 * 4;   // 33,554,432

  float* v1 = (float*)d_ws;
  float* vsum = v1 + 65536;
  float* partial = vsum + 65536;

  int chunks = 128;
  while (chunks > 8 &&
         (131072 + (size_t)chunks * 65536 + XP_FLOATS + WP_FLOATS) * 4 > ws_size)
    chunks >>= 1;
  bool packed_path =
      (131072 + (size_t)chunks * 65536 + XP_FLOATS + WP_FLOATS) * 4 <= ws_size;

  if (packed_path) {
    uint4* XP = (uint4*)(partial + (size_t)chunks * 65536);
    uint4* WP = XP + XP_FLOATS / 4;
    int NC = N_ / chunks;
    dim3 grid(chunks, 2);  // 2 bg-pairs; 2 b-groups fused per block

    prep_all<<<8704, 256, 0, stream>>>(W, x, WP, XP);

    mfma_pass2<1><<<grid, BLK, 0, stream>>>(XP, WP, nullptr, partial, NC);
    reduce_squash<<<256, 256, 0, stream>>>(partial, chunks, nullptr, v1);
    mfma_pass2<0><<<grid, BLK, 0, stream>>>(XP, WP, v1, partial, NC);
    reduce_squash<<<256, 256, 0, stream>>>(partial, chunks, v1, vsum);
    mfma_pass2<0><<<grid, BLK, 0, stream>>>(XP, WP, vsum, partial, NC);
    reduce_squash<<<256, 256, 0, stream>>>(partial, chunks, nullptr, out);
  } else {
    chunks = 128;
    while (chunks > 1 && (131072 + (size_t)chunks * 65536) * 4 > ws_size)
      chunks >>= 1;
    int NC = N_ / chunks;
    dim3 grid(chunks, 4);

    mfma_pass_fb<1><<<grid, 512, 0, stream>>>(x, W, nullptr, partial, NC);
    reduce_squash<<<256, 256, 0, stream>>>(partial, chunks, nullptr, v1);
    mfma_pass_fb<0><<<grid, 512, 0, stream>>>(x, W, v1, partial, NC);
    reduce_squash<<<256, 256, 0, stream>>>(partial, chunks, v1, vsum);
    mfma_pass_fb<0><<<grid, 512, 0, stream>>>(x, W, vsum, partial, NC);
    reduce_squash<<<256, 256, 0, stream>>>(partial, chunks, nullptr, out);
  }
}

// Round 6
// 486.896 us; speedup vs baseline: 1.0827x; 1.0827x over previous
//
#include <hip/hip_runtime.h>
#include <math.h>

#define B_ 64
#define N_ 2048
#define O_ 32
#define I_ 16
#define D_ 32
#define OD_ 1024

typedef __attribute__((ext_vector_type(8))) short bf16x8;
typedef __attribute__((ext_vector_type(4))) float f32x4;

union FragU { unsigned u[4]; uint4 v; bf16x8 f; };

__device__ __forceinline__ void dk_split(float f, unsigned &h, unsigned &l) {
  unsigned u = __float_as_uint(f);
  h = u & 0xffff0000u;
  float lo = f - __uint_as_float(h);
  l = __float_as_uint(lo) >> 16;
}

__device__ __forceinline__ void dk_split16(float f, unsigned short &h,
                                           unsigned short &l) {
  unsigned u = __float_as_uint(f);
  unsigned hu = u & 0xffff0000u;
  h = (unsigned short)(u >> 16);
  float lo = f - __uint_as_float(hu);
  l = (unsigned short)(__float_as_uint(lo) >> 16);
}

__device__ __forceinline__ unsigned pk(unsigned short e0, unsigned short e1) {
  return (unsigned)e0 | ((unsigned)e1 << 16);
}

// ---- merged prep: blocks [0,8192) pack W -> WP, [8192,8704) pack x -> XP ----
// WP u4 idx = (((n*32+o)*2 + dhalf)*4 + sel*2 + qp)*16 + c   (sel0=hi, sel1=lo)
// XP u4 idx = (((bg*2048+n)*2 + sel)*2 + qp)*16 + c ; b = bg*16 + c
__global__ __launch_bounds__(256) void prep_all(const float* __restrict__ W,
                                                const float* __restrict__ x,
                                                uint4* __restrict__ WP,
                                                uint4* __restrict__ XP) {
  if (blockIdx.x < 8192) {
    int t = blockIdx.x * 256 + threadIdx.x;  // 2,097,152 = n*o*d
    int d = t & 31, o = (t >> 5) & 31, n = t >> 10;
    const float* wp = W + ((size_t)(n * O_ + o) * I_) * D_ + d;
    unsigned short hh[I_], ll[I_];
#pragma unroll
    for (int i = 0; i < I_; ++i) dk_split16(wp[i * D_], hh[i], ll[i]);
    int c = d & 15, dhalf = d >> 4;
    size_t base = ((size_t)(n * O_ + o) * 2 + dhalf) * 4;
#pragma unroll
    for (int sel = 0; sel < 2; ++sel) {
      const unsigned short* e = sel ? ll : hh;
#pragma unroll
      for (int qp = 0; qp < 2; ++qp) {
        uint4 u;
        u.x = pk(e[qp * 8 + 0], e[qp * 8 + 1]);
        u.y = pk(e[qp * 8 + 2], e[qp * 8 + 3]);
        u.z = pk(e[qp * 8 + 4], e[qp * 8 + 5]);
        u.w = pk(e[qp * 8 + 6], e[qp * 8 + 7]);
        WP[(base + sel * 2 + qp) * 16 + c] = u;
      }
    }
  } else {
    int t = (blockIdx.x - 8192) * 256 + threadIdx.x;  // 131,072
    int c = t & 15, n = (t >> 4) & 2047, bg = t >> 15;
    const float* xp = x + ((size_t)(bg * 16 + c) * N_ + n) * I_;
    unsigned short hh[I_], ll[I_];
#pragma unroll
    for (int i = 0; i < I_; ++i) dk_split16(xp[i], hh[i], ll[i]);
    size_t base = ((size_t)bg * N_ + n) * 4;
#pragma unroll
    for (int sel = 0; sel < 2; ++sel) {
      const unsigned short* e = sel ? ll : hh;
#pragma unroll
      for (int qp = 0; qp < 2; ++qp) {
        uint4 u;
        u.x = pk(e[qp * 8 + 0], e[qp * 8 + 1]);
        u.y = pk(e[qp * 8 + 2], e[qp * 8 + 3]);
        u.z = pk(e[qp * 8 + 4], e[qp * 8 + 5]);
        u.w = pk(e[qp * 8 + 6], e[qp * 8 + 7]);
        XP[(base + sel * 2 + qp) * 16 + c] = u;
      }
    }
  }
}

// ---- fused routing pass, prefetched registers ----
// 16 waves/block; wave w covers o = 2w, 2w+1 (4 od-tiles). Block = 16 b x
// all 1024 od cols. grid (chunks, 4 b-groups). Register double-buffer: issue
// n+1 fragment loads before computing on n. v hoisted out of the n-loop.
template <int UNIFORM>
__global__ __launch_bounds__(1024, 4) void mfma_pass3(
    const uint4* __restrict__ XP, const uint4* __restrict__ WP,
    const float* __restrict__ v, float* __restrict__ partial, int NC) {
  const int tid = threadIdx.x;
  const int lane = tid & 63;
  const int w = tid >> 6;       // o-pair index 0..15
  const int q = lane >> 4;
  const int c = lane & 15;
  const int qp = q & 1;
  const int ch = blockIdx.x;
  const int bg = blockIdx.y;

  __shared__ float ls_logit[16 * O_];
  __shared__ float ls_c[16 * O_];

  f32x4 s_t[4];
#pragma unroll
  for (int ct = 0; ct < 4; ++ct) s_t[ct] = (f32x4){0.f, 0.f, 0.f, 0.f};

  // hoisted v fragments (loop-invariant): vreg[ct][r]
  float vreg[4][4];
  if (!UNIFORM) {
#pragma unroll
    for (int ct = 0; ct < 4; ++ct) {
      int odc = (2 * w + (ct >> 1)) * 32 + (ct & 1) * 16 + c;
#pragma unroll
      for (int r = 0; r < 4; ++r)
        vreg[ct][r] = v[(size_t)(bg * 16 + q * 4 + r) * OD_ + odc];
    }
  }

  const int n0 = ch * NC;
  // XP u4 index for (bg,n,sel,qp,c) = bg*N*64 + n*64 + sel*32 + qp*16 + c
  const uint4* xbase = XP + ((size_t)bg * N_) * 64 + qp * 16 + c;  // + n*64 (+32 for lo)
  const uint4* wbase0 = WP + ((size_t)(2 * w) * 2) * 64 + lane;    // + n*4096 + (o_l*2+dh)*64

  // prologue: load fragments for n0
  FragU cah, cal, cb[4];
  cah.v = xbase[(size_t)n0 * 64];
  cal.v = xbase[(size_t)n0 * 64 + 32];
#pragma unroll
  for (int ct = 0; ct < 4; ++ct)
    cb[ct].v = wbase0[(size_t)n0 * 4096 + ct * 64];

#pragma unroll 2
  for (int nl = 0; nl < NC; ++nl) {
    const int np = n0 + ((nl + 1 < NC) ? nl + 1 : nl);

    // ---- prefetch next iteration's fragments ----
    FragU nah, nal, nb[4];
    nah.v = xbase[(size_t)np * 64];
    nal.v = xbase[(size_t)np * 64 + 32];
#pragma unroll
    for (int ct = 0; ct < 4; ++ct)
      nb[ct].v = wbase0[(size_t)np * 4096 + ct * 64];

    // ---- MFMA on current fragments ----
    f32x4 u_t[4];
#pragma unroll
    for (int ct = 0; ct < 4; ++ct) {
      if (UNIFORM) {
        s_t[ct] = __builtin_amdgcn_mfma_f32_16x16x32_bf16(cah.f, cb[ct].f, s_t[ct], 0, 0, 0);
        s_t[ct] = __builtin_amdgcn_mfma_f32_16x16x32_bf16(cal.f, cb[ct].f, s_t[ct], 0, 0, 0);
      } else {
        f32x4 acc = (f32x4){0.f, 0.f, 0.f, 0.f};
        acc = __builtin_amdgcn_mfma_f32_16x16x32_bf16(cah.f, cb[ct].f, acc, 0, 0, 0);
        u_t[ct] = __builtin_amdgcn_mfma_f32_16x16x32_bf16(cal.f, cb[ct].f, acc, 0, 0, 0);
      }
    }

    if (!UNIFORM) {
      // logits: logit[b,o] = sum_d u*v ; d spans 2 tiles + 16 c-lanes
#pragma unroll
      for (int op = 0; op < 2; ++op) {
        float lg[4] = {0.f, 0.f, 0.f, 0.f};
#pragma unroll
        for (int hf = 0; hf < 2; ++hf) {
          int ct = op * 2 + hf;
#pragma unroll
          for (int r = 0; r < 4; ++r)
            lg[r] = fmaf(u_t[ct][r], vreg[ct][r], lg[r]);
        }
#pragma unroll
        for (int r = 0; r < 4; ++r) {
#pragma unroll
          for (int m = 1; m < 16; m <<= 1) lg[r] += __shfl_xor(lg[r], m);
        }
        if (c == 0) {
#pragma unroll
          for (int r = 0; r < 4; ++r)
            ls_logit[(q * 4 + r) * O_ + 2 * w + op] = lg[r];
        }
      }
      __syncthreads();
      // softmax over o: first 512 threads = 16 b x 32 o
      if (tid < 512) {
        int b_l = tid >> 5, o = tid & 31;
        float l = ls_logit[b_l * O_ + o];
        float mx = l;
#pragma unroll
        for (int m = 16; m >= 1; m >>= 1) mx = fmaxf(mx, __shfl_xor(mx, m));
        float e = __expf(l - mx);
        float sm = e;
#pragma unroll
        for (int m = 16; m >= 1; m >>= 1) sm += __shfl_xor(sm, m);
        ls_c[b_l * O_ + o] = e / sm;
      }
      __syncthreads();
      // s += c * u
#pragma unroll
      for (int ct = 0; ct < 4; ++ct) {
        int o = 2 * w + (ct >> 1);
#pragma unroll
        for (int r = 0; r < 4; ++r) {
          float cc = ls_c[(q * 4 + r) * O_ + o];
          s_t[ct][r] = fmaf(cc, u_t[ct][r], s_t[ct][r]);
        }
      }
    }

    // rotate buffers
    cah = nah;
    cal = nal;
#pragma unroll
    for (int ct = 0; ct < 4; ++ct) cb[ct] = nb[ct];
  }

  const float scale = UNIFORM ? (1.f / 32.f) : 1.f;
#pragma unroll
  for (int ct = 0; ct < 4; ++ct) {
    int odc = (2 * w + (ct >> 1)) * 32 + (ct & 1) * 16 + c;
#pragma unroll
    for (int r = 0; r < 4; ++r) {
      partial[((size_t)ch * B_ + bg * 16 + q * 4 + r) * OD_ + odc] =
          s_t[ct][r] * scale;
    }
  }
}

// ---- fallback (round-2 path, used only if ws too small for WP/XP) ----
template <int UNIFORM>
__global__ __launch_bounds__(512, 4) void mfma_pass_fb(
    const float* __restrict__ x, const float* __restrict__ W,
    const float* __restrict__ v, float* __restrict__ partial, int NC) {
  const int tid = threadIdx.x;
  const int lane = tid & 63;
  const int cg = tid >> 6;
  const int q = lane >> 4;
  const int c = lane & 15;
  const int ch = blockIdx.x;
  const int bg = blockIdx.y;

  __shared__ float ls_logit[16 * O_];
  __shared__ float ls_c[16 * O_];

  f32x4 s_t[8];
#pragma unroll
  for (int ct = 0; ct < 8; ++ct) s_t[ct] = (f32x4){0.f, 0.f, 0.f, 0.f};

  const int n0 = ch * NC;
  const int ih = (q & 1) * 8;
  const float* xrow = x + ((size_t)(bg * 16 + c) * N_) * I_ + ih;

  for (int nl = 0; nl < NC; ++nl) {
    const int n = n0 + nl;
    const float* xp = xrow + (size_t)n * I_;
    float4 xv0 = *(const float4*)xp;
    float4 xv1 = *(const float4*)(xp + 4);
    float xv[8] = {xv0.x, xv0.y, xv0.z, xv0.w, xv1.x, xv1.y, xv1.z, xv1.w};
    FragU a1;
#pragma unroll
    for (int p = 0; p < 4; ++p) {
      unsigned h0, l0, h1, l1;
      dk_split(xv[2 * p], h0, l0);
      dk_split(xv[2 * p + 1], h1, l1);
      a1.u[p] = (q < 2) ? ((h0 >> 16) | h1) : (l0 | (l1 << 16));
    }
    f32x4 u_t[8];
#pragma unroll
    for (int ct = 0; ct < 8; ++ct) {
      const int o = cg * 4 + (ct >> 1);
      const int d = (ct & 1) * 16 + c;
      const float* wp = W + (((size_t)n * O_ + o) * I_ + ih) * D_ + d;
      FragU b1, b2;
#pragma unroll
      for (int p = 0; p < 4; ++p) {
        unsigned h0, l0, h1, l1;
        dk_split(wp[(2 * p) * D_], h0, l0);
        dk_split(wp[(2 * p + 1) * D_], h1, l1);
        b1.u[p] = (h0 >> 16) | h1;
        b2.u[p] = l0 | (l1 << 16);
      }
      if (UNIFORM) {
        s_t[ct] = __builtin_amdgcn_mfma_f32_16x16x32_bf16(a1.f, b1.f, s_t[ct], 0, 0, 0);
        s_t[ct] = __builtin_amdgcn_mfma_f32_16x16x32_bf16(a1.f, b2.f, s_t[ct], 0, 0, 0);
      } else {
        f32x4 acc = (f32x4){0.f, 0.f, 0.f, 0.f};
        acc = __builtin_amdgcn_mfma_f32_16x16x32_bf16(a1.f, b1.f, acc, 0, 0, 0);
        u_t[ct] = __builtin_amdgcn_mfma_f32_16x16x32_bf16(a1.f, b2.f, acc, 0, 0, 0);
      }
    }
    if (!UNIFORM) {
#pragma unroll
      for (int ol = 0; ol < 4; ++ol) {
        float lg[4] = {0.f, 0.f, 0.f, 0.f};
#pragma unroll
        for (int hf = 0; hf < 2; ++hf) {
          int ct = ol * 2 + hf;
          int odc = cg * 128 + ct * 16 + c;
#pragma unroll
          for (int r = 0; r < 4; ++r)
            lg[r] = fmaf(u_t[ct][r], v[(size_t)(bg * 16 + q * 4 + r) * OD_ + odc], lg[r]);
        }
#pragma unroll
        for (int r = 0; r < 4; ++r) {
#pragma unroll
          for (int m = 1; m < 16; m <<= 1) lg[r] += __shfl_xor(lg[r], m);
        }
        if (c == 0) {
#pragma unroll
          for (int r = 0; r < 4; ++r)
            ls_logit[(q * 4 + r) * O_ + cg * 4 + ol] = lg[r];
        }
      }
      __syncthreads();
      {
        int b_l = tid >> 5, o = tid & 31;
        float l = ls_logit[b_l * O_ + o];
        float mx = l;
#pragma unroll
        for (int m = 16; m >= 1; m >>= 1) mx = fmaxf(mx, __shfl_xor(mx, m));
        float e = __expf(l - mx);
        float sm = e;
#pragma unroll
        for (int m = 16; m >= 1; m >>= 1) sm += __shfl_xor(sm, m);
        ls_c[b_l * O_ + o] = e / sm;
      }
      __syncthreads();
#pragma unroll
      for (int ol = 0; ol < 4; ++ol) {
        int o = cg * 4 + ol;
        float cc[4];
#pragma unroll
        for (int r = 0; r < 4; ++r) cc[r] = ls_c[(q * 4 + r) * O_ + o];
#pragma unroll
        for (int hf = 0; hf < 2; ++hf) {
          int ct = ol * 2 + hf;
#pragma unroll
          for (int r = 0; r < 4; ++r)
            s_t[ct][r] = fmaf(cc[r], u_t[ct][r], s_t[ct][r]);
        }
      }
    }
  }

  const float scale = UNIFORM ? (1.f / 32.f) : 1.f;
#pragma unroll
  for (int ct = 0; ct < 8; ++ct) {
#pragma unroll
    for (int r = 0; r < 4; ++r) {
      partial[((size_t)ch * B_ + bg * 16 + q * 4 + r) * OD_ + cg * 128 + ct * 16 + c] =
          s_t[ct][r] * scale;
    }
  }
}

// Sum partials over chunks (float4, unrolled), squash along d.
// out = (prev ? prev : 0) + squash(s); 8 threads per (b,o) row.
__global__ __launch_bounds__(256) void reduce_squash(
    const float4* __restrict__ part, int chunks,
    const float4* __restrict__ prev, float4* __restrict__ out) {
  int g4 = blockIdx.x * 256 + threadIdx.x;  // 16384 total
  float4 s = make_float4(0.f, 0.f, 0.f, 0.f);
#pragma unroll 4
  for (int ch = 0; ch < chunks; ++ch) {
    float4 p = part[(size_t)ch * 16384 + g4];
    s.x += p.x; s.y += p.y; s.z += p.z; s.w += p.w;
  }
  float sq = s.x * s.x + s.y * s.y + s.z * s.z + s.w * s.w;
#pragma unroll
  for (int m = 4; m >= 1; m >>= 1) sq += __shfl_xor(sq, m, 8);
  float scale = sq / ((1.f + sq) * (sqrtf(sq) + 1e-6f));
  float4 r = make_float4(s.x * scale, s.y * scale, s.z * scale, s.w * scale);
  if (prev) {
    float4 p = prev[g4];
    r.x += p.x; r.y += p.y; r.z += p.z; r.w += p.w;
  }
  out[g4] = r;
}

extern "C" void kernel_launch(void* const* d_in, const int* in_sizes, int n_in,
                              void* d_out, int out_size, void* d_ws,
                              size_t ws_size, hipStream_t stream) {
  const float* x = (const float*)d_in[0];
  const float* W = (const float*)d_in[1];
  float* out = (float*)d_out;

  const size_t XP_FLOATS = 4ull * 2048 * 4 * 16 * 4;        // 2,097,152
  const size_t WP_FLOATS = 2048ull * 32 * 2 * 4 * 16 * 4;   // 33,554,432

  float* v1 = (float*)d_ws;
  float* vsum = v1 + 65536;
  float* partial = vsum + 65536;

  int chunks = 128;
  while (chunks > 8 &&
         (131072 + (size_t)chunks * 65536 + XP_FLOATS + WP_FLOATS) * 4 > ws_size)
    chunks >>= 1;
  bool packed_path =
      (131072 + (size_t)chunks * 65536 + XP_FLOATS + WP_FLOATS) * 4 <= ws_size;

  if (packed_path) {
    uint4* XP = (uint4*)(partial + (size_t)chunks * 65536);
    uint4* WP = XP + XP_FLOATS / 4;
    int NC = N_ / chunks;
    dim3 grid(chunks, 4);

    prep_all<<<8704, 256, 0, stream>>>(W, x, WP, XP);

    mfma_pass3<1><<<grid, 1024, 0, stream>>>(XP, WP, nullptr, partial, NC);
    reduce_squash<<<64, 256, 0, stream>>>((const float4*)partial, chunks,
                                          nullptr, (float4*)v1);
    mfma_pass3<0><<<grid, 1024, 0, stream>>>(XP, WP, v1, partial, NC);
    reduce_squash<<<64, 256, 0, stream>>>((const float4*)partial, chunks,
                                          (const float4*)v1, (float4*)vsum);
    mfma_pass3<0><<<grid, 1024, 0, stream>>>(XP, WP, vsum, partial, NC);
    reduce_squash<<<64, 256, 0, stream>>>((const float4*)partial, chunks,
                                          nullptr, (float4*)out);
  } else {
    chunks = 128;
    while (chunks > 1 && (131072 + (size_t)chunks * 65536) * 4 > ws_size)
      chunks >>= 1;
    int NC = N_ / chunks;
    dim3 grid(chunks, 4);

    mfma_pass_fb<1><<<grid, 512, 0, stream>>>(x, W, nullptr, partial, NC);
    reduce_squash<<<64, 256, 0, stream>>>((const float4*)partial, chunks,
                                          nullptr, (float4*)v1);
    mfma_pass_fb<0><<<grid, 512, 0, stream>>>(x, W, v1, partial, NC);
    reduce_squash<<<64, 256, 0, stream>>>((const float4*)partial, chunks,
                                          (const float4*)v1, (float4*)vsum);
    mfma_pass_fb<0><<<grid, 512, 0, stream>>>(x, W, vsum, partial, NC);
    reduce_squash<<<64, 256, 0, stream>>>((const float4*)partial, chunks,
                                          nullptr, (float4*)out);
  }
}

// Round 7
// 483.861 us; speedup vs baseline: 1.0895x; 1.0063x over previous
//
#include <hip/hip_runtime.h>
#include <math.h>

#define B_ 64
#define N_ 2048
#define O_ 32
#define I_ 16
#define D_ 32
#define OD_ 1024

typedef __attribute__((ext_vector_type(8))) short bf16x8;
typedef __attribute__((ext_vector_type(4))) float f32x4;

union FragU { unsigned u[4]; uint4 v; bf16x8 f; };

__device__ __forceinline__ void dk_split(float f, unsigned &h, unsigned &l) {
  unsigned u = __float_as_uint(f);
  h = u & 0xffff0000u;
  float lo = f - __uint_as_float(h);
  l = __float_as_uint(lo) >> 16;
}

__device__ __forceinline__ void dk_split16(float f, unsigned short &h,
                                           unsigned short &l) {
  unsigned u = __float_as_uint(f);
  unsigned hu = u & 0xffff0000u;
  h = (unsigned short)(u >> 16);
  float lo = f - __uint_as_float(hu);
  l = (unsigned short)(__float_as_uint(lo) >> 16);
}

__device__ __forceinline__ unsigned pk(unsigned short e0, unsigned short e1) {
  return (unsigned)e0 | ((unsigned)e1 << 16);
}

// ---- merged prep: blocks [0,8192) pack W -> WP, [8192,8704) pack x -> XP ----
// WP u4 idx = (((n*32+o)*2 + dhalf)*4 + sel*2 + qp)*16 + c   (sel0=hi, sel1=lo)
// XP u4 idx = (((bg*2048+n)*2 + sel)*2 + qp)*16 + c ; b = bg*16 + c
__global__ __launch_bounds__(256) void prep_all(const float* __restrict__ W,
                                                const float* __restrict__ x,
                                                uint4* __restrict__ WP,
                                                uint4* __restrict__ XP) {
  if (blockIdx.x < 8192) {
    int t = blockIdx.x * 256 + threadIdx.x;  // 2,097,152 = n*o*d
    int d = t & 31, o = (t >> 5) & 31, n = t >> 10;
    const float* wp = W + ((size_t)(n * O_ + o) * I_) * D_ + d;
    unsigned short hh[I_], ll[I_];
#pragma unroll
    for (int i = 0; i < I_; ++i) dk_split16(wp[i * D_], hh[i], ll[i]);
    int c = d & 15, dhalf = d >> 4;
    size_t base = ((size_t)(n * O_ + o) * 2 + dhalf) * 4;
#pragma unroll
    for (int sel = 0; sel < 2; ++sel) {
      const unsigned short* e = sel ? ll : hh;
#pragma unroll
      for (int qp = 0; qp < 2; ++qp) {
        uint4 u;
        u.x = pk(e[qp * 8 + 0], e[qp * 8 + 1]);
        u.y = pk(e[qp * 8 + 2], e[qp * 8 + 3]);
        u.z = pk(e[qp * 8 + 4], e[qp * 8 + 5]);
        u.w = pk(e[qp * 8 + 6], e[qp * 8 + 7]);
        WP[(base + sel * 2 + qp) * 16 + c] = u;
      }
    }
  } else {
    int t = (blockIdx.x - 8192) * 256 + threadIdx.x;  // 131,072
    int c = t & 15, n = (t >> 4) & 2047, bg = t >> 15;
    const float* xp = x + ((size_t)(bg * 16 + c) * N_ + n) * I_;
    unsigned short hh[I_], ll[I_];
#pragma unroll
    for (int i = 0; i < I_; ++i) dk_split16(xp[i], hh[i], ll[i]);
    size_t base = ((size_t)bg * N_ + n) * 4;
#pragma unroll
    for (int sel = 0; sel < 2; ++sel) {
      const unsigned short* e = sel ? ll : hh;
#pragma unroll
      for (int qp = 0; qp < 2; ++qp) {
        uint4 u;
        u.x = pk(e[qp * 8 + 0], e[qp * 8 + 1]);
        u.y = pk(e[qp * 8 + 2], e[qp * 8 + 3]);
        u.z = pk(e[qp * 8 + 4], e[qp * 8 + 5]);
        u.w = pk(e[qp * 8 + 6], e[qp * 8 + 7]);
        XP[(base + sel * 2 + qp) * 16 + c] = u;
      }
    }
  }
}

// ---- fused routing pass, G=2 n-group batching ----
// 16 waves/block; wave w covers o = 2w, 2w+1 (4 od-tiles). Block = 16 b x
// 1024 od cols, grid (chunks, 4 b-groups). Per group: 12 batched fragment
// loads (deep MLP), 16 MFMAs, ONE logit+softmax+reweight round for both n's
// (2 barriers per 2 n's instead of per n). Softmax: 1024 rows = 1024 thr.
template <int UNIFORM>
__global__ __launch_bounds__(1024, 4) void mfma_pass4(
    const uint4* __restrict__ XP, const uint4* __restrict__ WP,
    const float* __restrict__ v, float* __restrict__ partial, int NC) {
  const int tid = threadIdx.x;
  const int lane = tid & 63;
  const int w = tid >> 6;       // o-pair index 0..15
  const int q = lane >> 4;
  const int c = lane & 15;
  const int qp = q & 1;
  const int ch = blockIdx.x;
  const int bg = blockIdx.y;

  __shared__ float ls_logit[2 * 16 * O_];
  __shared__ float ls_c[2 * 16 * O_];

  f32x4 s_t[4];
#pragma unroll
  for (int ct = 0; ct < 4; ++ct) s_t[ct] = (f32x4){0.f, 0.f, 0.f, 0.f};

  // hoisted v fragments (loop-invariant): vreg[ct][r]
  float vreg[4][4];
  if (!UNIFORM) {
#pragma unroll
    for (int ct = 0; ct < 4; ++ct) {
      int odc = (2 * w + (ct >> 1)) * 32 + (ct & 1) * 16 + c;
#pragma unroll
      for (int r = 0; r < 4; ++r)
        vreg[ct][r] = v[(size_t)(bg * 16 + q * 4 + r) * OD_ + odc];
    }
  }

  const int n0 = ch * NC;
  // XP u4 idx = bg*N*64 + n*64 + sel*32 + qp*16 + c
  const uint4* xbase = XP + ((size_t)bg * N_) * 64 + qp * 16 + c;
  // WP u4 idx = n*4096 + o*128 + dhalf*64 + rec*16 + c ; rec==q via +lane
  const uint4* wbase0 = WP + (size_t)(2 * w) * 128 + lane;

  for (int g = 0; g < NC / 2; ++g) {
    const size_t na = (size_t)(n0 + 2 * g);
    const size_t nb = na + 1;

    // ---- batched loads for both n's (12 x 1KB, issued together) ----
    FragU ah[2], al[2], bf[2][4];
    ah[0].v = xbase[na * 64];
    al[0].v = xbase[na * 64 + 32];
    ah[1].v = xbase[nb * 64];
    al[1].v = xbase[nb * 64 + 32];
#pragma unroll
    for (int ct = 0; ct < 4; ++ct) {
      bf[0][ct].v = wbase0[na * 4096 + ct * 64];
      bf[1][ct].v = wbase0[nb * 4096 + ct * 64];
    }

    // ---- MFMA for both n's ----
    f32x4 u_t[2][4];
#pragma unroll
    for (int nn = 0; nn < 2; ++nn) {
#pragma unroll
      for (int ct = 0; ct < 4; ++ct) {
        if (UNIFORM) {
          s_t[ct] = __builtin_amdgcn_mfma_f32_16x16x32_bf16(ah[nn].f, bf[nn][ct].f, s_t[ct], 0, 0, 0);
          s_t[ct] = __builtin_amdgcn_mfma_f32_16x16x32_bf16(al[nn].f, bf[nn][ct].f, s_t[ct], 0, 0, 0);
        } else {
          f32x4 acc = (f32x4){0.f, 0.f, 0.f, 0.f};
          acc = __builtin_amdgcn_mfma_f32_16x16x32_bf16(ah[nn].f, bf[nn][ct].f, acc, 0, 0, 0);
          u_t[nn][ct] = __builtin_amdgcn_mfma_f32_16x16x32_bf16(al[nn].f, bf[nn][ct].f, acc, 0, 0, 0);
        }
      }
    }

    if (!UNIFORM) {
      // ---- logits for both n's: logit[b,o] = sum_d u*v ----
#pragma unroll
      for (int nn = 0; nn < 2; ++nn) {
#pragma unroll
        for (int op = 0; op < 2; ++op) {
          float lg[4] = {0.f, 0.f, 0.f, 0.f};
#pragma unroll
          for (int hf = 0; hf < 2; ++hf) {
            int ct = op * 2 + hf;
#pragma unroll
            for (int r = 0; r < 4; ++r)
              lg[r] = fmaf(u_t[nn][ct][r], vreg[ct][r], lg[r]);
          }
#pragma unroll
          for (int r = 0; r < 4; ++r) {
#pragma unroll
            for (int m = 1; m < 16; m <<= 1) lg[r] += __shfl_xor(lg[r], m);
          }
          if (c == 0) {
#pragma unroll
            for (int r = 0; r < 4; ++r)
              ls_logit[nn * 512 + (q * 4 + r) * O_ + 2 * w + op] = lg[r];
          }
        }
      }
      __syncthreads();
      // ---- softmax: 1024 rows (2n x 16b x 32o) = 1024 threads ----
      {
        float l = ls_logit[tid];
        float mx = l;
#pragma unroll
        for (int m = 16; m >= 1; m >>= 1) mx = fmaxf(mx, __shfl_xor(mx, m));
        float e = __expf(l - mx);
        float sm = e;
#pragma unroll
        for (int m = 16; m >= 1; m >>= 1) sm += __shfl_xor(sm, m);
        ls_c[tid] = e / sm;
      }
      __syncthreads();
      // ---- s += c * u for both n's ----
#pragma unroll
      for (int nn = 0; nn < 2; ++nn) {
#pragma unroll
        for (int ct = 0; ct < 4; ++ct) {
          int o = 2 * w + (ct >> 1);
#pragma unroll
          for (int r = 0; r < 4; ++r) {
            float cc = ls_c[nn * 512 + (q * 4 + r) * O_ + o];
            s_t[ct][r] = fmaf(cc, u_t[nn][ct][r], s_t[ct][r]);
          }
        }
      }
    }
  }

  const float scale = UNIFORM ? (1.f / 32.f) : 1.f;
#pragma unroll
  for (int ct = 0; ct < 4; ++ct) {
    int odc = (2 * w + (ct >> 1)) * 32 + (ct & 1) * 16 + c;
#pragma unroll
    for (int r = 0; r < 4; ++r) {
      partial[((size_t)ch * B_ + bg * 16 + q * 4 + r) * OD_ + odc] =
          s_t[ct][r] * scale;
    }
  }
}

// ---- fallback (round-2 path, used only if ws too small for WP/XP) ----
template <int UNIFORM>
__global__ __launch_bounds__(512, 4) void mfma_pass_fb(
    const float* __restrict__ x, const float* __restrict__ W,
    const float* __restrict__ v, float* __restrict__ partial, int NC) {
  const int tid = threadIdx.x;
  const int lane = tid & 63;
  const int cg = tid >> 6;
  const int q = lane >> 4;
  const int c = lane & 15;
  const int ch = blockIdx.x;
  const int bg = blockIdx.y;

  __shared__ float ls_logit[16 * O_];
  __shared__ float ls_c[16 * O_];

  f32x4 s_t[8];
#pragma unroll
  for (int ct = 0; ct < 8; ++ct) s_t[ct] = (f32x4){0.f, 0.f, 0.f, 0.f};

  const int n0 = ch * NC;
  const int ih = (q & 1) * 8;
  const float* xrow = x + ((size_t)(bg * 16 + c) * N_) * I_ + ih;

  for (int nl = 0; nl < NC; ++nl) {
    const int n = n0 + nl;
    const float* xp = xrow + (size_t)n * I_;
    float4 xv0 = *(const float4*)xp;
    float4 xv1 = *(const float4*)(xp + 4);
    float xv[8] = {xv0.x, xv0.y, xv0.z, xv0.w, xv1.x, xv1.y, xv1.z, xv1.w};
    FragU a1;
#pragma unroll
    for (int p = 0; p < 4; ++p) {
      unsigned h0, l0, h1, l1;
      dk_split(xv[2 * p], h0, l0);
      dk_split(xv[2 * p + 1], h1, l1);
      a1.u[p] = (q < 2) ? ((h0 >> 16) | h1) : (l0 | (l1 << 16));
    }
    f32x4 u_t[8];
#pragma unroll
    for (int ct = 0; ct < 8; ++ct) {
      const int o = cg * 4 + (ct >> 1);
      const int d = (ct & 1) * 16 + c;
      const float* wp = W + (((size_t)n * O_ + o) * I_ + ih) * D_ + d;
      FragU b1, b2;
#pragma unroll
      for (int p = 0; p < 4; ++p) {
        unsigned h0, l0, h1, l1;
        dk_split(wp[(2 * p) * D_], h0, l0);
        dk_split(wp[(2 * p + 1) * D_], h1, l1);
        b1.u[p] = (h0 >> 16) | h1;
        b2.u[p] = l0 | (l1 << 16);
      }
      if (UNIFORM) {
        s_t[ct] = __builtin_amdgcn_mfma_f32_16x16x32_bf16(a1.f, b1.f, s_t[ct], 0, 0, 0);
        s_t[ct] = __builtin_amdgcn_mfma_f32_16x16x32_bf16(a1.f, b2.f, s_t[ct], 0, 0, 0);
      } else {
        f32x4 acc = (f32x4){0.f, 0.f, 0.f, 0.f};
        acc = __builtin_amdgcn_mfma_f32_16x16x32_bf16(a1.f, b1.f, acc, 0, 0, 0);
        u_t[ct] = __builtin_amdgcn_mfma_f32_16x16x32_bf16(a1.f, b2.f, acc, 0, 0, 0);
      }
    }
    if (!UNIFORM) {
#pragma unroll
      for (int ol = 0; ol < 4; ++ol) {
        float lg[4] = {0.f, 0.f, 0.f, 0.f};
#pragma unroll
        for (int hf = 0; hf < 2; ++hf) {
          int ct = ol * 2 + hf;
          int odc = cg * 128 + ct * 16 + c;
#pragma unroll
          for (int r = 0; r < 4; ++r)
            lg[r] = fmaf(u_t[ct][r], v[(size_t)(bg * 16 + q * 4 + r) * OD_ + odc], lg[r]);
        }
#pragma unroll
        for (int r = 0; r < 4; ++r) {
#pragma unroll
          for (int m = 1; m < 16; m <<= 1) lg[r] += __shfl_xor(lg[r], m);
        }
        if (c == 0) {
#pragma unroll
          for (int r = 0; r < 4; ++r)
            ls_logit[(q * 4 + r) * O_ + cg * 4 + ol] = lg[r];
        }
      }
      __syncthreads();
      {
        int b_l = tid >> 5, o = tid & 31;
        float l = ls_logit[b_l * O_ + o];
        float mx = l;
#pragma unroll
        for (int m = 16; m >= 1; m >>= 1) mx = fmaxf(mx, __shfl_xor(mx, m));
        float e = __expf(l - mx);
        float sm = e;
#pragma unroll
        for (int m = 16; m >= 1; m >>= 1) sm += __shfl_xor(sm, m);
        ls_c[b_l * O_ + o] = e / sm;
      }
      __syncthreads();
#pragma unroll
      for (int ol = 0; ol < 4; ++ol) {
        int o = cg * 4 + ol;
        float cc[4];
#pragma unroll
        for (int r = 0; r < 4; ++r) cc[r] = ls_c[(q * 4 + r) * O_ + o];
#pragma unroll
        for (int hf = 0; hf < 2; ++hf) {
          int ct = ol * 2 + hf;
#pragma unroll
          for (int r = 0; r < 4; ++r)
            s_t[ct][r] = fmaf(cc[r], u_t[ct][r], s_t[ct][r]);
        }
      }
    }
  }

  const float scale = UNIFORM ? (1.f / 32.f) : 1.f;
#pragma unroll
  for (int ct = 0; ct < 8; ++ct) {
#pragma unroll
    for (int r = 0; r < 4; ++r) {
      partial[((size_t)ch * B_ + bg * 16 + q * 4 + r) * OD_ + cg * 128 + ct * 16 + c] =
          s_t[ct][r] * scale;
    }
  }
}

// Sum partials over chunks (float4, unrolled), squash along d.
// out = (prev ? prev : 0) + squash(s); 8 threads per (b,o) row.
__global__ __launch_bounds__(256) void reduce_squash(
    const float4* __restrict__ part, int chunks,
    const float4* __restrict__ prev, float4* __restrict__ out) {
  int g4 = blockIdx.x * 256 + threadIdx.x;  // 16384 total
  float4 s = make_float4(0.f, 0.f, 0.f, 0.f);
#pragma unroll 4
  for (int ch = 0; ch < chunks; ++ch) {
    float4 p = part[(size_t)ch * 16384 + g4];
    s.x += p.x; s.y += p.y; s.z += p.z; s.w += p.w;
  }
  float sq = s.x * s.x + s.y * s.y + s.z * s.z + s.w * s.w;
#pragma unroll
  for (int m = 4; m >= 1; m >>= 1) sq += __shfl_xor(sq, m, 8);
  float scale = sq / ((1.f + sq) * (sqrtf(sq) + 1e-6f));
  float4 r = make_float4(s.x * scale, s.y * scale, s.z * scale, s.w * scale);
  if (prev) {
    float4 p = prev[g4];
    r.x += p.x; r.y += p.y; r.z += p.z; r.w += p.w;
  }
  out[g4] = r;
}

extern "C" void kernel_launch(void* const* d_in, const int* in_sizes, int n_in,
                              void* d_out, int out_size, void* d_ws,
                              size_t ws_size, hipStream_t stream) {
  const float* x = (const float*)d_in[0];
  const float* W = (const float*)d_in[1];
  float* out = (float*)d_out;

  const size_t XP_FLOATS = 4ull * 2048 * 4 * 16 * 4;        // 2,097,152
  const size_t WP_FLOATS = 2048ull * 32 * 2 * 4 * 16 * 4;   // 33,554,432

  float* v1 = (float*)d_ws;
  float* vsum = v1 + 65536;
  float* partial = vsum + 65536;

  int chunks = 128;
  while (chunks > 8 &&
         (131072 + (size_t)chunks * 65536 + XP_FLOATS + WP_FLOATS) * 4 > ws_size)
    chunks >>= 1;
  bool packed_path =
      (131072 + (size_t)chunks * 65536 + XP_FLOATS + WP_FLOATS) * 4 <= ws_size;

  if (packed_path) {
    uint4* XP = (uint4*)(partial + (size_t)chunks * 65536);
    uint4* WP = XP + XP_FLOATS / 4;
    int NC = N_ / chunks;
    dim3 grid(chunks, 4);

    prep_all<<<8704, 256, 0, stream>>>(W, x, WP, XP);

    mfma_pass4<1><<<grid, 1024, 0, stream>>>(XP, WP, nullptr, partial, NC);
    reduce_squash<<<64, 256, 0, stream>>>((const float4*)partial, chunks,
                                          nullptr, (float4*)v1);
    mfma_pass4<0><<<grid, 1024, 0, stream>>>(XP, WP, v1, partial, NC);
    reduce_squash<<<64, 256, 0, stream>>>((const float4*)partial, chunks,
                                          (const float4*)v1, (float4*)vsum);
    mfma_pass4<0><<<grid, 1024, 0, stream>>>(XP, WP, vsum, partial, NC);
    reduce_squash<<<64, 256, 0, stream>>>((const float4*)partial, chunks,
                                          nullptr, (float4*)out);
  } else {
    chunks = 128;
    while (chunks > 1 && (131072 + (size_t)chunks * 65536) * 4 > ws_size)
      chunks >>= 1;
    int NC = N_ / chunks;
    dim3 grid(chunks, 4);

    mfma_pass_fb<1><<<grid, 512, 0, stream>>>(x, W, nullptr, partial, NC);
    reduce_squash<<<64, 256, 0, stream>>>((const float4*)partial, chunks,
                                          nullptr, (float4*)v1);
    mfma_pass_fb<0><<<grid, 512, 0, stream>>>(x, W, v1, partial, NC);
    reduce_squash<<<64, 256, 0, stream>>>((const float4*)partial, chunks,
                                          (const float4*)v1, (float4*)vsum);
    mfma_pass_fb<0><<<grid, 512, 0, stream>>>(x, W, vsum, partial, NC);
    reduce_squash<<<64, 256, 0, stream>>>((const float4*)partial, chunks,
                                          nullptr, (float4*)out);
  }
}